// Round 9
// baseline (139.469 us; speedup 1.0000x reference)
//
#include <hip/hip_runtime.h>
#include <hip/hip_bf16.h>

#define CC 64
#define NN 4096   // H*W
#define MM 1024   // pooled pixels

typedef __attribute__((ext_vector_type(4))) short s4b;      // 4 bf16 = 2 VGPRs
typedef __attribute__((ext_vector_type(4))) float float4v;  // MFMA C/D frag

__device__ inline unsigned short f2bf(float f) {
    union { float f; unsigned u; } v; v.f = f;
    unsigned r = v.u + 0x7fff + ((v.u >> 16) & 1);   // RNE
    return (unsigned short)(r >> 16);
}

__device__ inline float4v mfma16(s4b a, s4b b, float4v c) {
#if __has_builtin(__builtin_amdgcn_mfma_f32_16x16x16bf16_1k)
    return __builtin_amdgcn_mfma_f32_16x16x16bf16_1k(a, b, c, 0, 0, 0);
#else
    float4v d;
    asm volatile("v_mfma_f32_16x16x16_bf16 %0, %1, %2, %3"
                 : "=v"(d) : "v"(a), "v"(b), "v"(c));
    return d;
#endif
}

// ---------------------------------------------------------------------------
// prep_kernel (unchanged from R6): 2 c-halves per pixel (reduced via LDS),
// 512 blocks, 8 waves/CU, 16 loads in flight per wave.
// Outputs: thT [b][n][8] bf16 (x log2e); phiP [b][m][8]; gP [b][gi][m].
// ---------------------------------------------------------------------------
__global__ __launch_bounds__(256) void prep_kernel(
    const float* __restrict__ x,
    const float* __restrict__ Wth,
    const float* __restrict__ Wph,
    const float* __restrict__ Wg,
    unsigned short* __restrict__ thT,
    unsigned short* __restrict__ phiP,
    unsigned short* __restrict__ gP)
{
    __shared__ float wt[64 * 48];       // 12.3 KB
    __shared__ float buf[128 * 49];     // 25.1 KB (partials, then pool)

    const int tid  = threadIdx.x;
    const int b    = blockIdx.y;
    const int hp   = blockIdx.x;        // row-pair 0..31
    const int pix  = tid & 127;         // 2 rows x 64 cols
    const int half = tid >> 7;          // c-half (wave-uniform)

    for (int idx = tid; idx < 64 * 48; idx += 256) {
        const int c = idx / 48, j = idx % 48;
        float v;
        if (j < 8)       v = Wth[j * 64 + c];
        else if (j < 16) v = Wph[(j - 8) * 64 + c];
        else             v = Wg[(j - 16) * 64 + c];
        wt[c * 48 + j] = v;
    }
    __syncthreads();

    const int n = (2 * hp + (pix >> 6)) * 64 + (pix & 63);
    const float* xb = x + (size_t)b * CC * NN + (size_t)half * 32 * NN + n;

    float acc[48];
#pragma unroll
    for (int j = 0; j < 48; ++j) acc[j] = 0.f;

#pragma unroll
    for (int c0 = 0; c0 < 32; c0 += 16) {
        float xv[16];
#pragma unroll
        for (int u = 0; u < 16; ++u) xv[u] = xb[(size_t)(c0 + u) * NN];
#pragma unroll
        for (int u = 0; u < 16; ++u) {
            const float* wrow = &wt[(half * 32 + c0 + u) * 48];
#pragma unroll
            for (int j = 0; j < 48; ++j) acc[j] += wrow[j] * xv[u];
        }
    }

    if (half == 1) {
#pragma unroll
        for (int j = 0; j < 48; ++j) buf[pix * 49 + j] = acc[j];
    }
    __syncthreads();

    if (half == 0) {
#pragma unroll
        for (int j = 0; j < 48; ++j) acc[j] += buf[pix * 49 + j];
        union { unsigned short s[8]; uint4 v; } pk;
#pragma unroll
        for (int j = 0; j < 8; ++j) pk.s[j] = f2bf(acc[j] * 1.44269504f);
        *(uint4*)&thT[((size_t)b * NN + n) * 8] = pk.v;
#pragma unroll
        for (int j = 0; j < 40; ++j) buf[pix * 49 + j] = acc[8 + j];
    }
    __syncthreads();

    for (int idx = tid; idx < 1280; idx += 256) {
        const int pm = idx & 31;        // pooled col
        const int j  = idx >> 5;        // channel 0..39
        const int p00 = 2 * pm, p10 = 64 + 2 * pm;
        const float v = fmaxf(fmaxf(buf[p00 * 49 + j], buf[(p00 + 1) * 49 + j]),
                              fmaxf(buf[p10 * 49 + j], buf[(p10 + 1) * 49 + j]));
        const int m = hp * 32 + pm;
        if (j < 8) phiP[((size_t)b * MM + m) * 8 + j] = f2bf(v);
        else       gP[((size_t)b * 32 + (j - 8)) * MM + m] = f2bf(v);
    }
}

// ---------------------------------------------------------------------------
// attn_mfma v6 = R6 structure (16 q/wave, 1024 blocks, 16 waves/CU) with phi
// moved OUT of LDS: each step's phi A-frag is loaded directly from global
// into registers in fragment arrangement (16 uint2 loads/chunk, issued
// before the chunk's barriers so the L2 latency overlaps g staging).
// Removes the chain-leading ds_read from every step, cuts per-step LDS
// reads 3->2, and drops phi staging. Registers live only within a chunk
// (unlike the failed R7/R8 prefetch). Grid (64,16), block 256.
// ---------------------------------------------------------------------------
__global__ __launch_bounds__(256) void attn_mfma(
    const unsigned short* __restrict__ thT,   // [B][N][8]
    const unsigned short* __restrict__ phiP,  // [B][M][8]
    const unsigned short* __restrict__ gP,    // [B][32][M]
    const float* __restrict__ x,
    const float* __restrict__ Wa,             // [64][32]
    const float* __restrict__ sigma,
    float* __restrict__ out)
{
    constexpr int GP = 264;   // g_s pitch (bf16): 528 B = 33x16 (aligned rows)
    constexpr int OP = 36;    // obar pitch (f32)

    __shared__ __align__(16) union {
        unsigned short g[32 * GP];              // 16.5 KB
        float obar[64 * OP];                    // 9.2 KB
    } sh;
    __shared__ __align__(16) float wa_s[64 * 32];   // 8 KB

    const int tid  = threadIdx.x;
    const int lane = tid & 63;
    const int wv   = tid >> 6;
    const int c15  = lane & 15;     // score D col = query; PV D col = gi
    const int quad = lane >> 4;
    const int b    = blockIdx.y;
    const int n0   = blockIdx.x * 64;

    for (int i = tid; i < 2048; i += 256) wa_s[i] = Wa[i];

    // theta B-frag (const): B[k=quad*4+j][n=q]; real only for quads 0,1 (k<8)
    s4b zero4 = {0, 0, 0, 0};
    s4b bth = zero4;
    if (quad < 2) {
        union { uint2 u; s4b s; } t;
        t.u = *(const uint2*)&thT[((size_t)b * NN + n0 + wv * 16 + c15) * 8 + quad * 4];
        bth = t.s;
    }

    float4v acc0 = {0.f, 0.f, 0.f, 0.f};
    float4v acc1 = {0.f, 0.f, 0.f, 0.f};
    float zacc = 0.f;

    // per-lane phi fragment base: quads 2,3 overread into the next key's
    // data (finite, in-bounds of d_ws) and are zeroed by the theta half
    const unsigned short* phi_lane = phiP + ((size_t)b * MM + c15) * 8 + quad * 4;

    for (int ch = 0; ch < 4; ++ch) {
        // issue this chunk's 16 phi A-frags straight into registers; the
        // L2-hit latency overlaps the barrier + g staging below
        uint2 pf[16];
#pragma unroll
        for (int st = 0; st < 16; ++st)
            pf[st] = *(const uint2*)(phi_lane + (size_t)(ch * 256 + st * 16) * 8);

        __syncthreads();   // previous chunk's g readers done
        // stage g: 32 rows x 256 bf16 = 1024 uint4
#pragma unroll
        for (int it = 0; it < 4; ++it) {
            const int idx = tid + 256 * it;
            const int row = idx >> 5, c32 = idx & 31;
            *(uint4*)&sh.g[row * GP + c32 * 8] =
                *(const uint4*)&gP[((size_t)b * 32 + row) * MM + ch * 256 + c32 * 8];
        }
        __syncthreads();

#pragma unroll 4
        for (int st = 0; st < 16; ++st) {
            const int kb = st * 16;   // key base within chunk

            union { uint2 u; s4b s; } ap;
            ap.u = pf[st];

            float4v cz = {0.f, 0.f, 0.f, 0.f};
            float4v sc = mfma16(ap.s, bth, cz);   // D[key=quad*4+r][query=c15]

            // exp2 + Z + pack P (truncating bf16) -> PV A-frag in-register
            union { float f; unsigned u; } e0, e1, e2, e3;
            e0.f = __builtin_amdgcn_exp2f(sc[0]);
            e1.f = __builtin_amdgcn_exp2f(sc[1]);
            e2.f = __builtin_amdgcn_exp2f(sc[2]);
            e3.f = __builtin_amdgcn_exp2f(sc[3]);
            zacc += (e0.f + e1.f) + (e2.f + e3.f);
            union { uint2 u; s4b s; } pa;
            pa.u.x = __builtin_amdgcn_perm(e1.u, e0.u, 0x07060302u);
            pa.u.y = __builtin_amdgcn_perm(e3.u, e2.u, 0x07060302u);

            // g B-frags: B[k=quad*4+j][n=gi=c15] = g[gi][kb+quad*4+j]
            union { uint2 u; s4b s; } bg0, bg1;
            bg0.u = *(const uint2*)&sh.g[c15 * GP + kb + quad * 4];
            bg1.u = *(const uint2*)&sh.g[(16 + c15) * GP + kb + quad * 4];

            acc0 = mfma16(pa.s, bg0.s, acc0);   // D[q=quad*4+r][gi=c15]
            acc1 = mfma16(pa.s, bg1.s, acc1);   // gi = c15+16
        }
    }

    // full Z per query at every lane (q = c15)
    float z = zacc;
    z += __shfl_xor(z, 16, 64);
    z += __shfl_xor(z, 32, 64);
    const float rzq = __builtin_amdgcn_rcpf(z);

    __syncthreads();   // main-loop LDS reads done before obar overwrites

#pragma unroll
    for (int r = 0; r < 4; ++r) {
        const float rz = __shfl(rzq, quad * 4 + r, 64);  // Z of query quad*4+r
        const int ql = wv * 16 + quad * 4 + r;
        sh.obar[ql * OP + c15]      = acc0[r] * rz;
        sh.obar[ql * OP + 16 + c15] = acc1[r] * rz;
    }
    __syncthreads();

    // epilogue: out[o][n] = x + sigma * Wa[o][:] . obar[q][:]
    {
        const int q  = tid & 63;
        const int og = tid >> 6;    // 4 groups of 16 channels
        float a[16];
#pragma unroll
        for (int i = 0; i < 16; ++i) a[i] = 0.f;
        const float4* ob4 = (const float4*)&sh.obar[q * OP];   // 144 B pitch, 16B-aligned
        const float4* wa4 = (const float4*)wa_s;
#pragma unroll
        for (int g4 = 0; g4 < 8; ++g4) {
            const float4 ob = ob4[g4];
#pragma unroll
            for (int i = 0; i < 16; ++i) {
                const float4 w = wa4[(og * 16 + i) * 8 + g4];
                a[i] += w.x * ob.x + w.y * ob.y + w.z * ob.z + w.w * ob.w;
            }
        }
        const float sg = sigma[0];
#pragma unroll
        for (int i = 0; i < 16; ++i) {
            const size_t oi = ((size_t)b * CC + og * 16 + i) * NN + n0 + q;
            out[oi] = x[oi] + sg * a[i];
        }
    }
}

extern "C" void kernel_launch(void* const* d_in, const int* in_sizes, int n_in,
                              void* d_out, int out_size, void* d_ws, size_t ws_size,
                              hipStream_t stream) {
    const float* x      = (const float*)d_in[0];
    const float* W_th   = (const float*)d_in[1];
    const float* W_ph   = (const float*)d_in[2];
    const float* W_g    = (const float*)d_in[3];
    const float* W_attn = (const float*)d_in[4];
    const float* sigma  = (const float*)d_in[5];
    float* out = (float*)d_out;

    const int B = 16;
    unsigned short* thT  = (unsigned short*)d_ws;              // B*N*8
    unsigned short* phiP = thT + (size_t)B * NN * 8;           // B*M*8
    unsigned short* gP   = phiP + (size_t)B * MM * 8;          // B*32*M

    prep_kernel<<<dim3(32, 16), 256, 0, stream>>>(x, W_th, W_ph, W_g,
                                                  thT, phiP, gP);
    attn_mfma<<<dim3(64, 16), 256, 0, stream>>>(thT, phiP, gP, x,
                                                W_attn, sigma, out);
}

// Round 10
// 116.262 us; speedup vs baseline: 1.1996x; 1.1996x over previous
//
#include <hip/hip_runtime.h>
#include <hip/hip_bf16.h>

#define CC 64
#define NN 4096   // H*W
#define MM 1024   // pooled pixels

typedef __attribute__((ext_vector_type(4))) short s4b;      // 4 bf16 = 2 VGPRs
typedef __attribute__((ext_vector_type(4))) float float4v;  // MFMA C/D frag

__device__ inline unsigned short f2bf(float f) {
    union { float f; unsigned u; } v; v.f = f;
    unsigned r = v.u + 0x7fff + ((v.u >> 16) & 1);   // RNE
    return (unsigned short)(r >> 16);
}

__device__ inline float4v mfma16(s4b a, s4b b, float4v c) {
#if __has_builtin(__builtin_amdgcn_mfma_f32_16x16x16bf16_1k)
    return __builtin_amdgcn_mfma_f32_16x16x16bf16_1k(a, b, c, 0, 0, 0);
#else
    float4v d;
    asm volatile("v_mfma_f32_16x16x16_bf16 %0, %1, %2, %3"
                 : "=v"(d) : "v"(a), "v"(b), "v"(c));
    return d;
#endif
}

// ---------------------------------------------------------------------------
// prep_kernel: 2 c-halves per pixel (reduced via LDS) -> 512 blocks,
// 8 waves/CU, 16 loads in flight per wave: BW-bound on the 64 MB x read.
// Block: 256 thr = 128 pixels (2 rows x 64 cols) x 2 c-halves. Grid (32,16).
// Outputs: thT [b][n][8] bf16 (x log2e); phiP [b][m][8]; gP [b][gi][m].
// ---------------------------------------------------------------------------
__global__ __launch_bounds__(256) void prep_kernel(
    const float* __restrict__ x,
    const float* __restrict__ Wth,
    const float* __restrict__ Wph,
    const float* __restrict__ Wg,
    unsigned short* __restrict__ thT,
    unsigned short* __restrict__ phiP,
    unsigned short* __restrict__ gP)
{
    __shared__ float wt[64 * 48];       // 12.3 KB
    __shared__ float buf[128 * 49];     // 25.1 KB (partials, then pool)

    const int tid  = threadIdx.x;
    const int b    = blockIdx.y;
    const int hp   = blockIdx.x;        // row-pair 0..31
    const int pix  = tid & 127;         // 2 rows x 64 cols
    const int half = tid >> 7;          // c-half (wave-uniform)

    for (int idx = tid; idx < 64 * 48; idx += 256) {
        const int c = idx / 48, j = idx % 48;
        float v;
        if (j < 8)       v = Wth[j * 64 + c];
        else if (j < 16) v = Wph[(j - 8) * 64 + c];
        else             v = Wg[(j - 16) * 64 + c];
        wt[c * 48 + j] = v;
    }
    __syncthreads();

    const int n = (2 * hp + (pix >> 6)) * 64 + (pix & 63);
    const float* xb = x + (size_t)b * CC * NN + (size_t)half * 32 * NN + n;

    float acc[48];
#pragma unroll
    for (int j = 0; j < 48; ++j) acc[j] = 0.f;

#pragma unroll
    for (int c0 = 0; c0 < 32; c0 += 16) {
        float xv[16];
#pragma unroll
        for (int u = 0; u < 16; ++u) xv[u] = xb[(size_t)(c0 + u) * NN];
#pragma unroll
        for (int u = 0; u < 16; ++u) {
            const float* wrow = &wt[(half * 32 + c0 + u) * 48];
#pragma unroll
            for (int j = 0; j < 48; ++j) acc[j] += wrow[j] * xv[u];
        }
    }

    if (half == 1) {
#pragma unroll
        for (int j = 0; j < 48; ++j) buf[pix * 49 + j] = acc[j];
    }
    __syncthreads();

    if (half == 0) {
#pragma unroll
        for (int j = 0; j < 48; ++j) acc[j] += buf[pix * 49 + j];
        union { unsigned short s[8]; uint4 v; } pk;
#pragma unroll
        for (int j = 0; j < 8; ++j) pk.s[j] = f2bf(acc[j] * 1.44269504f);
        *(uint4*)&thT[((size_t)b * NN + n) * 8] = pk.v;
#pragma unroll
        for (int j = 0; j < 40; ++j) buf[pix * 49 + j] = acc[8 + j];
    }
    __syncthreads();

    for (int idx = tid; idx < 1280; idx += 256) {
        const int pm = idx & 31;        // pooled col
        const int j  = idx >> 5;        // channel 0..39
        const int p00 = 2 * pm, p10 = 64 + 2 * pm;
        const float v = fmaxf(fmaxf(buf[p00 * 49 + j], buf[(p00 + 1) * 49 + j]),
                              fmaxf(buf[p10 * 49 + j], buf[(p10 + 1) * 49 + j]));
        const int m = hp * 32 + pm;
        if (j < 8) phiP[((size_t)b * MM + m) * 8 + j] = f2bf(v);
        else       gP[((size_t)b * 32 + (j - 8)) * MM + m] = f2bf(v);
    }
}

// ---------------------------------------------------------------------------
// attn_mfma v3b (R6, best measured = 115.1 us total): block = 64 queries
// (4 waves x 16), each wave runs ALL 1024 keys for its 16 queries. K=16
// MFMAs keep P entirely in registers (score D layout == PV A layout).
// phi+g staged via fully-coalesced uint4 loads -> LDS each 256-key chunk.
// NOTE: v4 (32 q/wave), v5 (register staging prefetch) and v6 (phi direct
// from global) ALL regressed — occupancy loss / register pressure /
// coalescing loss respectively. This configuration is the local optimum.
// Grid (64,16), block 256.
// ---------------------------------------------------------------------------
__global__ __launch_bounds__(256) void attn_mfma(
    const unsigned short* __restrict__ thT,   // [B][N][8]
    const unsigned short* __restrict__ phiP,  // [B][M][8]
    const unsigned short* __restrict__ gP,    // [B][32][M]
    const float* __restrict__ x,
    const float* __restrict__ Wa,             // [64][32]
    const float* __restrict__ sigma,
    float* __restrict__ out)
{
    constexpr int GP = 264;   // g_s pitch (bf16): 528 B = 33x16 (aligned rows)
    constexpr int OP = 36;    // obar pitch (f32)

    __shared__ __align__(16) union {
        struct {
            unsigned short phi[256 * 8 + 16];  // pad: key-255 quad2/3 overread
            unsigned short g[32 * GP];
        } m;                                    // 21.0 KB
        float obar[64 * OP];                    // 9.2 KB
    } sh;
    __shared__ __align__(16) float wa_s[64 * 32];   // 8 KB

    const int tid  = threadIdx.x;
    const int lane = tid & 63;
    const int wv   = tid >> 6;
    const int c15  = lane & 15;     // score D col = query; PV D col = gi
    const int quad = lane >> 4;
    const int b    = blockIdx.y;
    const int n0   = blockIdx.x * 64;

    for (int i = tid; i < 2048; i += 256) wa_s[i] = Wa[i];

    // theta B-frag (const): B[k=quad*4+j][n=q]; real only for quads 0,1 (k<8)
    s4b zero4 = {0, 0, 0, 0};
    s4b bth = zero4;
    if (quad < 2) {
        union { uint2 u; s4b s; } t;
        t.u = *(const uint2*)&thT[((size_t)b * NN + n0 + wv * 16 + c15) * 8 + quad * 4];
        bth = t.s;
    }

    float4v acc0 = {0.f, 0.f, 0.f, 0.f};
    float4v acc1 = {0.f, 0.f, 0.f, 0.f};
    float zacc = 0.f;

    for (int ch = 0; ch < 4; ++ch) {
        __syncthreads();
        // stage phi: 256 keys x 8 bf16 (one uint4/thread) + zero the pad
        *(uint4*)&sh.m.phi[tid * 8] =
            *(const uint4*)&phiP[((size_t)b * MM + ch * 256 + tid) * 8];
        if (tid < 2) {
            uint4 z4; z4.x = z4.y = z4.z = z4.w = 0u;
            *(uint4*)&sh.m.phi[256 * 8 + tid * 8] = z4;
        }
        // stage g: 32 rows x 256 bf16 = 1024 uint4
#pragma unroll
        for (int it = 0; it < 4; ++it) {
            const int idx = tid + 256 * it;
            const int row = idx >> 5, c32 = idx & 31;
            *(uint4*)&sh.m.g[row * GP + c32 * 8] =
                *(const uint4*)&gP[((size_t)b * 32 + row) * MM + ch * 256 + c32 * 8];
        }
        __syncthreads();

#pragma unroll 4
        for (int st = 0; st < 16; ++st) {
            const int kb = st * 16;   // key base within chunk

            // phi A-frag: A[m=key=c15][k=quad*4+j] (quads 2,3 read the next
            // key's finite data; theta B is zero there so it contributes 0)
            union { uint2 u; s4b s; } ap;
            ap.u = *(const uint2*)&sh.m.phi[(kb + c15) * 8 + quad * 4];

            float4v cz = {0.f, 0.f, 0.f, 0.f};
            float4v sc = mfma16(ap.s, bth, cz);   // D[key=quad*4+r][query=c15]

            // exp2 + Z + pack P (truncating bf16) -> PV A-frag in-register
            union { float f; unsigned u; } e0, e1, e2, e3;
            e0.f = __builtin_amdgcn_exp2f(sc[0]);
            e1.f = __builtin_amdgcn_exp2f(sc[1]);
            e2.f = __builtin_amdgcn_exp2f(sc[2]);
            e3.f = __builtin_amdgcn_exp2f(sc[3]);
            zacc += (e0.f + e1.f) + (e2.f + e3.f);
            union { uint2 u; s4b s; } pa;
            pa.u.x = __builtin_amdgcn_perm(e1.u, e0.u, 0x07060302u);
            pa.u.y = __builtin_amdgcn_perm(e3.u, e2.u, 0x07060302u);

            // g B-frags: B[k=quad*4+j][n=gi=c15] = g[gi][kb+quad*4+j]
            union { uint2 u; s4b s; } bg0, bg1;
            bg0.u = *(const uint2*)&sh.m.g[c15 * GP + kb + quad * 4];
            bg1.u = *(const uint2*)&sh.m.g[(16 + c15) * GP + kb + quad * 4];

            acc0 = mfma16(pa.s, bg0.s, acc0);   // D[q=quad*4+r][gi=c15]
            acc1 = mfma16(pa.s, bg1.s, acc1);   // gi = c15+16
        }
    }

    // full Z per query at every lane (q = c15)
    float z = zacc;
    z += __shfl_xor(z, 16, 64);
    z += __shfl_xor(z, 32, 64);
    const float rzq = __builtin_amdgcn_rcpf(z);

    __syncthreads();   // main-loop LDS reads done before obar overwrites

#pragma unroll
    for (int r = 0; r < 4; ++r) {
        const float rz = __shfl(rzq, quad * 4 + r, 64);  // Z of query quad*4+r
        const int ql = wv * 16 + quad * 4 + r;
        sh.obar[ql * OP + c15]      = acc0[r] * rz;
        sh.obar[ql * OP + 16 + c15] = acc1[r] * rz;
    }
    __syncthreads();

    // epilogue: out[o][n] = x + sigma * Wa[o][:] . obar[q][:]
    {
        const int q  = tid & 63;
        const int og = tid >> 6;    // 4 groups of 16 channels
        float a[16];
#pragma unroll
        for (int i = 0; i < 16; ++i) a[i] = 0.f;
        const float4* ob4 = (const float4*)&sh.obar[q * OP];   // 144 B pitch, 16B-aligned
        const float4* wa4 = (const float4*)wa_s;
#pragma unroll
        for (int g4 = 0; g4 < 8; ++g4) {
            const float4 ob = ob4[g4];
#pragma unroll
            for (int i = 0; i < 16; ++i) {
                const float4 w = wa4[(og * 16 + i) * 8 + g4];
                a[i] += w.x * ob.x + w.y * ob.y + w.z * ob.z + w.w * ob.w;
            }
        }
        const float sg = sigma[0];
#pragma unroll
        for (int i = 0; i < 16; ++i) {
            const size_t oi = ((size_t)b * CC + og * 16 + i) * NN + n0 + q;
            out[oi] = x[oi] + sg * a[i];
        }
    }
}

extern "C" void kernel_launch(void* const* d_in, const int* in_sizes, int n_in,
                              void* d_out, int out_size, void* d_ws, size_t ws_size,
                              hipStream_t stream) {
    const float* x      = (const float*)d_in[0];
    const float* W_th   = (const float*)d_in[1];
    const float* W_ph   = (const float*)d_in[2];
    const float* W_g    = (const float*)d_in[3];
    const float* W_attn = (const float*)d_in[4];
    const float* sigma  = (const float*)d_in[5];
    float* out = (float*)d_out;

    const int B = 16;
    unsigned short* thT  = (unsigned short*)d_ws;              // B*N*8
    unsigned short* phiP = thT + (size_t)B * NN * 8;           // B*M*8
    unsigned short* gP   = phiP + (size_t)B * MM * 8;          // B*32*M

    prep_kernel<<<dim3(32, 16), 256, 0, stream>>>(x, W_th, W_ph, W_g,
                                                  thT, phiP, gP);
    attn_mfma<<<dim3(64, 16), 256, 0, stream>>>(thT, phiP, gP, x,
                                                W_attn, sigma, out);
}